// Round 5
// baseline (238.959 us; speedup 1.0000x reference)
//
#include <hip/hip_runtime.h>
#include <math.h>

constexpr int B = 2, H = 320, W = 512, D = 64;
constexpr int HW = H * W;
constexpr int R = 10;             // BLOCK // 2
constexpr int SEG = 80, NSEG = 4; // 320 = 4*80
constexpr int VS = 536;           // vsum row stride (words): [12 zeros][512 data][12 zeros]
constexpr float EPS = 1e-12f;

// Normalize one tensor (6ch -> L/R float4 planes).
__global__ void k_norm(const float* __restrict__ src, float4* __restrict__ nrm4) {
    int idx = blockIdx.x * 256 + threadIdx.x;
    if (idx >= B * HW) return;
    int b = idx / HW, hw = idx - b * HW;
    const float* p = src + (size_t)b * 6 * HW + hw;
    float v0 = p[0],      v1 = p[HW],     v2 = p[2 * HW];
    float v3 = p[3 * HW], v4 = p[4 * HW], v5 = p[5 * HW];
    float n1 = fmaxf(sqrtf(v0 * v0 + v1 * v1 + v2 * v2), EPS);
    float n2 = fmaxf(sqrtf(v3 * v3 + v4 * v4 + v5 * v5), EPS);
    float4* q = nrm4 + (size_t)b * 2 * HW + hw;
    q[0]  = make_float4(v0 / n1, v1 / n1, v2 / n1, 0.f);
    q[HW] = make_float4(v3 / n2, v4 / n2, v5 / n2, 0.f);
}

// Diff + vertical 21-row rolling sum. Ring lives in REGISTERS (full unroll ->
// static slot indices). No LDS, no barriers. Writes zero-padded vsum rows.
// blk&7 -> (b,seg) pins all 64 d of a row-band to one XCD for L2 reuse.
__global__ __launch_bounds__(512) void k_vsum(const float4* __restrict__ nrm4,
                                              float* __restrict__ vsum) {
    int blk = blockIdx.x;
    int combo = blk & 7, d = blk >> 3;
    int b = combo >> 2, seg = combo & 3;
    int w = threadIdx.x;
    const float4* L4 = nrm4 + (size_t)b * 2 * HW;
    const float4* R4 = L4 + HW;
    const bool val = (w >= d);
    const int wr = val ? (w - d) : 0;
    const int h0 = seg * SEG;

    auto diff = [&](int h) -> float {
        float4 l = L4[(size_t)h * W + w];
        float4 r = R4[(size_t)h * W + wr];
        float a = fabsf(l.x - r.x) + fabsf(l.y - r.y) + fabsf(l.z - r.z);
        float s = fabsf(l.x) + fabsf(l.y) + fabsf(l.z);  // r_shift == 0 when invalid
        return val ? a : s;
    };

    float ring[21];
    float vs = 0.f;
#pragma unroll
    for (int k = 0; k < 20; ++k) {        // window rows [h0-10, h0+9]
        int h = h0 - R + k;
        float dv = diff(h < 0 ? 0 : h);
        if (h < 0) dv = 0.f;
        ring[k] = dv;
        vs += dv;
    }
    ring[20] = 0.f;                       // slot for row h0-11 (subtracts 0 first)

    float* vp = vsum + (size_t)((b * D + d) * H) * VS;
#pragma unroll
    for (int i = 0; i < SEG; ++i) {       // full unroll: ring indices all static
        int h = h0 + i;
        int slot = (i + 20) % 21;
        int hn = h + R;
        float dv = diff(hn < H ? hn : H - 1);
        if (hn >= H) dv = 0.f;
        float dold = ring[slot];
        ring[slot] = dv;
        vs += dv - dold;                  // window now [h-10, h+10]
        float* row = vp + (size_t)h * VS;
        row[12 + w] = vs;
        if (w < 12) { row[w] = 0.f; row[524 + w] = 0.f; }
    }
}

// Horizontal 21-col rolling sum + argmin over d + (optional) fused |d1-d0| loss.
// Block = (b,h) row: 8 waves; wave dd handles d = dd+8k; lane cc owns output
// cols 8cc..8cc+7 via a 32-word aligned window (8x float4). Lexicographic
// (val,d) merge across waves keeps the lowest tied d (jnp.argmin semantics).
__global__ __launch_bounds__(512) void k_harg(const float* __restrict__ vsum,
                                              float* __restrict__ disp,
                                              const float* __restrict__ disp0,
                                              float* __restrict__ part) {
    int blk = blockIdx.x;
    int combo = blk & 7, hh = blk >> 3;   // combo matches k_vsum's XCD pinning
    int b = combo >> 2, seg = combo & 3;
    int h = seg * SEG + hh;
    int dd = threadIdx.x >> 6;            // wave 0..7
    int cc = threadIdx.x & 63;            // col-run 0..63

    __shared__ float sv[8][64][8];
    __shared__ int   sd[8][64][8];

    const float* rowb = vsum + ((size_t)(b * D) * H + h) * VS;
    float best[8]; int bestd[8];
#pragma unroll
    for (int k2 = 0; k2 < 8; ++k2) {
        int d = dd + 8 * k2;              // ascending d per thread
        const float4* rp = (const float4*)(rowb + (size_t)d * H * VS) + 2 * cc;
        float wnd[32];
#pragma unroll
        for (int q = 0; q < 8; ++q) {
            float4 v = rp[q];
            wnd[4 * q] = v.x; wnd[4 * q + 1] = v.y;
            wnd[4 * q + 2] = v.z; wnd[4 * q + 3] = v.w;
        }
        // wnd[j] = padded word 8cc+j = data col 8cc+j-12; output col 8cc+k sums wnd[k+2..k+22]
        float o = 0.f;
#pragma unroll
        for (int j = 2; j <= 22; ++j) o += wnd[j];
        float c[8];
        c[0] = o;
#pragma unroll
        for (int k = 1; k < 8; ++k) { o += wnd[k + 22] - wnd[k + 1]; c[k] = o; }
        if (k2 == 0) {
#pragma unroll
            for (int j = 0; j < 8; ++j) { best[j] = c[j]; bestd[j] = d; }
        } else {
#pragma unroll
            for (int j = 0; j < 8; ++j)
                if (c[j] < best[j]) { best[j] = c[j]; bestd[j] = d; }  // strict <
        }
    }
#pragma unroll
    for (int j = 0; j < 8; ++j) { sv[dd][cc][j] = best[j]; sd[dd][cc][j] = bestd[j]; }
    __syncthreads();

    int col = threadIdx.x;
    int c6 = col >> 3, c7 = col & 7;
    float bv = sv[0][c6][c7]; int bd = sd[0][c6][c7];
#pragma unroll
    for (int q = 1; q < 8; ++q) {
        float v = sv[q][c6][c7]; int dq = sd[q][c6][c7];
        if (v < bv || (v == bv && dq < bd)) { bv = v; bd = dq; }
    }
    float dres = (float)bd;
    size_t oidx = (size_t)(b * H + h) * W + col;
    if (disp0 == nullptr) {
        disp[oidx] = dres;
    } else {
        float ls = fabsf(dres - disp0[oidx]);
        __syncthreads();
        float* sm = &sv[0][0][0];
        sm[col] = ls;
        __syncthreads();
        for (int off = 256; off; off >>= 1) {
            if (col < off) sm[col] += sm[col + off];
            __syncthreads();
        }
        if (!col) part[blk] = sm[0];
    }
}

__global__ void k_red2(const float* __restrict__ part, float* __restrict__ out,
                       int nb, float inv) {
    __shared__ float sm[256];
    int tid = threadIdx.x;
    float s = 0.f;
    for (int i = tid; i < nb; i += 256) s += part[i];
    sm[tid] = s;
    __syncthreads();
    for (int off = 128; off; off >>= 1) {
        if (tid < off) sm[tid] += sm[tid + off];
        __syncthreads();
    }
    if (!tid) out[0] = sm[0] * inv;
}

extern "C" void kernel_launch(void* const* d_in, const int* in_sizes, int n_in,
                              void* d_out, int out_size, void* d_ws, size_t ws_size,
                              hipStream_t stream) {
    const float* x  = (const float*)d_in[0];
    const float* gt = (const float*)d_in[1];

    float4* nrm4 = (float4*)d_ws;                          // B*2*HW float4 = 10.5 MB
    float* vsum  = (float*)(nrm4 + (size_t)B * 2 * HW);    // B*D*H*VS f32  = 87.8 MB
    float* disp0 = vsum + (size_t)B * D * H * VS;          // B*HW f32      = 2.6 MB
    float* part  = disp0 + (size_t)B * HW;                 // 640 f32

    constexpr int NRM_BLKS = (B * HW + 255) / 256;         // 2560

    // t=0 : x -> disp0
    k_norm<<<NRM_BLKS, 256, 0, stream>>>(x, nrm4);
    k_vsum<<<B * NSEG * D, 512, 0, stream>>>(nrm4, vsum);
    k_harg<<<8 * SEG, 512, 0, stream>>>(vsum, disp0, nullptr, nullptr);

    // t=1 : gt -> argmin fused with |d1 - d0| partial sums
    k_norm<<<NRM_BLKS, 256, 0, stream>>>(gt, nrm4);
    k_vsum<<<B * NSEG * D, 512, 0, stream>>>(nrm4, vsum);
    k_harg<<<8 * SEG, 512, 0, stream>>>(vsum, nullptr, disp0, part);

    k_red2<<<1, 256, 0, stream>>>(part, (float*)d_out, 8 * SEG, 1.f / (float)(B * HW));
}